// Round 6
// baseline (422.658 us; speedup 1.0000x reference)
//
#include <hip/hip_runtime.h>
#include <math.h>

#define N_NODES 100000
#define N_EDGES 1600000
#define IN_FEAT 128
#define HIDDEN 64
#define N_CLASSES 16

#define CHUNK 512
#define NB ((N_NODES + CHUNK - 1) / CHUNK)  // 196

#define NSLICE 8
#define SLICE_SZ ((N_NODES + NSLICE - 1) / NSLICE)  // 12500
#define EPB 1024
#define NCHUNK ((N_EDGES + EPB - 1) / EPB)

#define TM 64
#define GBLK ((N_NODES + TM - 1) / TM)  // 1563

#define NBUK 196                        // buckets of 512 nodes (dst>>9)
#define CB 4096                         // edges per coarse block
#define NCB ((N_EDGES + CB - 1) / CB)   // 391

// ---------------- degree ----------------

__global__ void zero_deg_k(int* __restrict__ deg) {
    int i = blockIdx.x * blockDim.x + threadIdx.x;
    if (i < N_NODES) deg[i] = 0;
}

__global__ __launch_bounds__(256) void hist_sliced_k(const int* __restrict__ dst,
                                                     int* __restrict__ deg) {
    int slice = blockIdx.x & (NSLICE - 1);
    int chunk = blockIdx.x >> 3;
    int lo = slice * SLICE_SZ;
    int hi = lo + SLICE_SZ;
    int base = chunk * EPB + threadIdx.x * 4;
    if (base >= N_EDGES) return;
    int4 d4 = ((const int4*)dst)[base >> 2];
    if (d4.x >= lo && d4.x < hi) atomicAdd(&deg[d4.x], 1);
    if (d4.y >= lo && d4.y < hi) atomicAdd(&deg[d4.y], 1);
    if (d4.z >= lo && d4.z < hi) atomicAdd(&deg[d4.z], 1);
    if (d4.w >= lo && d4.w < hi) atomicAdd(&deg[d4.w], 1);
}

__global__ void dinv_k(const int* __restrict__ deg, float* __restrict__ dinv) {
    int i = blockIdx.x * blockDim.x + threadIdx.x;
    if (i < N_NODES) dinv[i] = 1.0f / sqrtf((float)(deg[i] + 1));
}

// ---------------- row_ptr (hierarchical scan) ----------------

__global__ __launch_bounds__(256) void chunk_sum_k(const int* __restrict__ deg,
                                                   int* __restrict__ blk_sum) {
    __shared__ int sm[256];
    int b = blockIdx.x, t = threadIdx.x;
    int i0 = b * CHUNK + t;
    int v = 0;
    if (i0 < N_NODES) v += deg[i0];
    if (i0 + 256 < N_NODES) v += deg[i0 + 256];
    sm[t] = v;
    __syncthreads();
    for (int s = 128; s > 0; s >>= 1) {
        if (t < s) sm[t] += sm[t + s];
        __syncthreads();
    }
    if (t == 0) blk_sum[b] = sm[0];
}

__global__ __launch_bounds__(256) void scan_blocks_k(const int* __restrict__ blk_sum,
                                                     int* __restrict__ blk_off,
                                                     int* __restrict__ row_ptr) {
    __shared__ int sm[256];
    int t = threadIdx.x;
    int v = (t < NB) ? blk_sum[t] : 0;
    sm[t] = v;
    __syncthreads();
    for (int s = 1; s < 256; s <<= 1) {
        int add = (t >= s) ? sm[t - s] : 0;
        __syncthreads();
        sm[t] += add;
        __syncthreads();
    }
    if (t < NB) blk_off[t] = sm[t] - v;
    if (t == 0) row_ptr[N_NODES] = N_EDGES;
}

__global__ __launch_bounds__(256) void rowptr_k(const int* __restrict__ deg,
                                                const int* __restrict__ blk_off,
                                                int* __restrict__ row_ptr) {
    __shared__ int pair[256];
    int b = blockIdx.x, t = threadIdx.x;
    int i0 = b * CHUNK + 2 * t;
    int d0 = (i0 < N_NODES) ? deg[i0] : 0;
    int d1 = (i0 + 1 < N_NODES) ? deg[i0 + 1] : 0;
    int p = d0 + d1;
    pair[t] = p;
    __syncthreads();
    for (int s = 1; s < 256; s <<= 1) {
        int add = (t >= s) ? pair[t - s] : 0;
        __syncthreads();
        pair[t] += add;
        __syncthreads();
    }
    int excl = pair[t] - p + blk_off[b];
    if (i0 < N_NODES)     row_ptr[i0]     = excl;
    if (i0 + 1 < N_NODES) row_ptr[i0 + 1] = excl + d0;
}

__global__ void bcur_init_k(const int* __restrict__ row_ptr, int* __restrict__ bcur) {
    int b = blockIdx.x * blockDim.x + threadIdx.x;
    if (b < NBUK) bcur[b] = row_ptr[b * 512];
}

// ---------------- coarse partition: group edges by 512-node bucket ----------------

__global__ __launch_bounds__(256) void coarse_k(const int* __restrict__ src,
                                                const int* __restrict__ dst,
                                                int* __restrict__ bcur,
                                                int2* __restrict__ pairs) {
    __shared__ int hist[NBUK + 4], loff[NBUK + 4], cur[NBUK + 4], gbase[NBUK + 4];
    __shared__ int sc[256];
    __shared__ int2 stage[CB];  // 32 KB
    int tid = threadIdx.x;
    int eb = blockIdx.x * CB;
    int nvalid = N_EDGES - eb;
    if (nvalid > CB) nvalid = CB;

    if (tid < NBUK) hist[tid] = 0;
    __syncthreads();

    int4 s4[4], d4[4];
    #pragma unroll
    for (int q = 0; q < 4; ++q) {
        int e4 = (eb >> 2) + tid + q * 256;
        if (e4 * 4 < N_EDGES) {
            s4[q] = ((const int4*)src)[e4];
            d4[q] = ((const int4*)dst)[e4];
        } else {
            d4[q] = make_int4(-1, -1, -1, -1);
            s4[q] = make_int4(0, 0, 0, 0);
        }
    }
    #pragma unroll
    for (int q = 0; q < 4; ++q) {
        if (d4[q].x >= 0) {
            atomicAdd(&hist[d4[q].x >> 9], 1);
            atomicAdd(&hist[d4[q].y >> 9], 1);
            atomicAdd(&hist[d4[q].z >> 9], 1);
            atomicAdd(&hist[d4[q].w >> 9], 1);
        }
    }
    __syncthreads();

    int v = (tid < NBUK) ? hist[tid] : 0;
    sc[tid] = v;
    __syncthreads();
    for (int s = 1; s < 256; s <<= 1) {
        int add = (tid >= s) ? sc[tid - s] : 0;
        __syncthreads();
        sc[tid] += add;
        __syncthreads();
    }
    if (tid < NBUK) {
        int excl = sc[tid] - v;
        loff[tid] = excl;
        cur[tid] = excl;
        gbase[tid] = atomicAdd(&bcur[tid], v);
    }
    __syncthreads();

    #pragma unroll
    for (int q = 0; q < 4; ++q) {
        if (d4[q].x >= 0) {
            int b, r;
            b = d4[q].x >> 9; r = atomicAdd(&cur[b], 1); stage[r] = make_int2(s4[q].x, d4[q].x);
            b = d4[q].y >> 9; r = atomicAdd(&cur[b], 1); stage[r] = make_int2(s4[q].y, d4[q].y);
            b = d4[q].z >> 9; r = atomicAdd(&cur[b], 1); stage[r] = make_int2(s4[q].z, d4[q].z);
            b = d4[q].w >> 9; r = atomicAdd(&cur[b], 1); stage[r] = make_int2(s4[q].w, d4[q].w);
        }
    }
    __syncthreads();

    for (int i = tid; i < nvalid; i += 256) {
        int2 p = stage[i];
        int b = p.y >> 9;
        pairs[gbase[b] + (i - loff[b])] = p;
    }
}

// ---------------- fine fill: per-bucket CSR placement ----------------

__global__ __launch_bounds__(256) void fine_k(const int2* __restrict__ pairs,
                                              const int* __restrict__ row_ptr,
                                              int* __restrict__ csr_src) {
    __shared__ int cur[512];
    int b = blockIdx.x;
    int node0 = b * 512;
    int nn = N_NODES - node0;
    if (nn > 512) nn = 512;
    int tid = threadIdx.x;
    for (int j = tid; j < nn; j += 256) cur[j] = row_ptr[node0 + j];
    __syncthreads();
    int e0 = row_ptr[node0];
    int e1 = row_ptr[node0 + nn];
    for (int e = e0 + tid; e < e1; e += 256) {
        int2 p = pairs[e];
        int pos = atomicAdd(&cur[p.y - node0], 1);
        csr_src[pos] = p.x;
    }
}

// ---------------- register-tiled GEMM 1: hws = (x @ W1) * dinv[row] ----------------

__global__ __launch_bounds__(256) void gemm1_tiled_k(const float* __restrict__ x,
                                                     const float* __restrict__ W,
                                                     const float* __restrict__ dinv,
                                                     float* __restrict__ hws) {
    __shared__ float Ws[64][64];
    __shared__ float xt[64][68];
    int tid = threadIdx.x;
    int row0 = blockIdx.x * TM;
    int rgrp4 = (tid >> 4) * 4;
    int cgrp4 = (tid & 15) * 4;

    float acc[4][4];
    #pragma unroll
    for (int r = 0; r < 4; ++r)
        #pragma unroll
        for (int c = 0; c < 4; ++c) acc[r][c] = 0.0f;

    for (int k0 = 0; k0 < IN_FEAT; k0 += 64) {
        #pragma unroll
        for (int i = 0; i < 4; ++i) {
            int f4 = tid + i * 256;
            int kk = f4 >> 4, c4 = (f4 & 15) * 4;
            *(float4*)&Ws[kk][c4] = *(const float4*)&W[(size_t)(k0 + kk) * HIDDEN + c4];
        }
        #pragma unroll
        for (int i = 0; i < 4; ++i) {
            int f4 = tid + i * 256;
            int rr = f4 >> 4, kq = (f4 & 15) * 4;
            int row = row0 + rr;
            if (row >= N_NODES) row = N_NODES - 1;
            float4 v = *(const float4*)&x[(size_t)row * IN_FEAT + k0 + kq];
            xt[kq + 0][rr] = v.x; xt[kq + 1][rr] = v.y;
            xt[kq + 2][rr] = v.z; xt[kq + 3][rr] = v.w;
        }
        __syncthreads();

        #pragma unroll 16
        for (int kk = 0; kk < 64; ++kk) {
            float4 a = *(const float4*)&xt[kk][rgrp4];
            float4 b = *(const float4*)&Ws[kk][cgrp4];
            acc[0][0] += a.x * b.x; acc[0][1] += a.x * b.y; acc[0][2] += a.x * b.z; acc[0][3] += a.x * b.w;
            acc[1][0] += a.y * b.x; acc[1][1] += a.y * b.y; acc[1][2] += a.y * b.z; acc[1][3] += a.y * b.w;
            acc[2][0] += a.z * b.x; acc[2][1] += a.z * b.y; acc[2][2] += a.z * b.z; acc[2][3] += a.z * b.w;
            acc[3][0] += a.w * b.x; acc[3][1] += a.w * b.y; acc[3][2] += a.w * b.z; acc[3][3] += a.w * b.w;
        }
        __syncthreads();
    }

    #pragma unroll
    for (int r = 0; r < 4; ++r) {
        int row = row0 + rgrp4 + r;
        if (row < N_NODES) {
            float dn = dinv[row];
            float4 o = make_float4(acc[r][0] * dn, acc[r][1] * dn, acc[r][2] * dn, acc[r][3] * dn);
            *(float4*)&hws[(size_t)row * HIDDEN + cgrp4] = o;
        }
    }
}

// ---------------- register-tiled GEMM 2: hws = (relu(agg) @ W2) * dinv[row] ----------------

__global__ __launch_bounds__(256) void gemm2_tiled_k(const float* __restrict__ agg,
                                                     const float* __restrict__ W,
                                                     const float* __restrict__ dinv,
                                                     float* __restrict__ hws) {
    __shared__ float Ws[64][64];
    __shared__ float xt[64][68];
    int tid = threadIdx.x;
    int row0 = blockIdx.x * TM;
    int rgrp4 = (tid >> 4) * 4;
    int cgrp4 = (tid & 15) * 4;

    #pragma unroll
    for (int i = 0; i < 4; ++i) {
        int f4 = tid + i * 256;
        int kk = f4 >> 4, c4 = (f4 & 15) * 4;
        *(float4*)&Ws[kk][c4] = *(const float4*)&W[(size_t)kk * HIDDEN + c4];
    }
    #pragma unroll
    for (int i = 0; i < 4; ++i) {
        int f4 = tid + i * 256;
        int rr = f4 >> 4, kq = (f4 & 15) * 4;
        int row = row0 + rr;
        if (row >= N_NODES) row = N_NODES - 1;
        float4 v = *(const float4*)&agg[(size_t)row * HIDDEN + kq];
        xt[kq + 0][rr] = fmaxf(v.x, 0.f); xt[kq + 1][rr] = fmaxf(v.y, 0.f);
        xt[kq + 2][rr] = fmaxf(v.z, 0.f); xt[kq + 3][rr] = fmaxf(v.w, 0.f);
    }
    __syncthreads();

    float acc[4][4];
    #pragma unroll
    for (int r = 0; r < 4; ++r)
        #pragma unroll
        for (int c = 0; c < 4; ++c) acc[r][c] = 0.0f;

    #pragma unroll 16
    for (int kk = 0; kk < 64; ++kk) {
        float4 a = *(const float4*)&xt[kk][rgrp4];
        float4 b = *(const float4*)&Ws[kk][cgrp4];
        acc[0][0] += a.x * b.x; acc[0][1] += a.x * b.y; acc[0][2] += a.x * b.z; acc[0][3] += a.x * b.w;
        acc[1][0] += a.y * b.x; acc[1][1] += a.y * b.y; acc[1][2] += a.y * b.z; acc[1][3] += a.y * b.w;
        acc[2][0] += a.z * b.x; acc[2][1] += a.z * b.y; acc[2][2] += a.z * b.z; acc[2][3] += a.z * b.w;
        acc[3][0] += a.w * b.x; acc[3][1] += a.w * b.y; acc[3][2] += a.w * b.z; acc[3][3] += a.w * b.w;
    }

    #pragma unroll
    for (int r = 0; r < 4; ++r) {
        int row = row0 + rgrp4 + r;
        if (row < N_NODES) {
            float dn = dinv[row];
            float4 o = make_float4(acc[r][0] * dn, acc[r][1] * dn, acc[r][2] * dn, acc[r][3] * dn);
            *(float4*)&hws[(size_t)row * HIDDEN + cgrp4] = o;
        }
    }
}

// ---------------- CSR pull: agg[d] = b + dinv[d]*(hws[d] + sum_in hws[s]) ----------------
// one wave per node; group g (16 lanes) owns edges i+4g..i+4g+3 per iteration:
// 4 independent index loads + 4 independent 256B gathers in flight per group.

__global__ __launch_bounds__(256) void pull_k(const int* __restrict__ row_ptr,
                                              const int* __restrict__ csr_src,
                                              const float* __restrict__ dinv,
                                              const float4* __restrict__ hws4,
                                              const float4* __restrict__ b4,
                                              float4* __restrict__ agg4) {
    int node = (blockIdx.x * 256 + threadIdx.x) >> 6;
    int lane = threadIdx.x & 63;
    int g = lane >> 4;
    int fl = lane & 15;
    if (node >= N_NODES) return;

    int start = row_ptr[node];
    int end = row_ptr[node + 1];

    float4 acc = make_float4(0.f, 0.f, 0.f, 0.f);
    if (g == 0) acc = hws4[(size_t)node * 16 + fl];

    for (int i = start; i < end; i += 16) {
        int e0 = i + g * 4;
        #pragma unroll
        for (int j = 0; j < 4; ++j) {
            int e = e0 + j;
            if (e < end) {
                int s = csr_src[e];
                float4 v = hws4[(size_t)s * 16 + fl];
                acc.x += v.x; acc.y += v.y; acc.z += v.z; acc.w += v.w;
            }
        }
    }

    #pragma unroll
    for (int m = 16; m <= 32; m <<= 1) {
        acc.x += __shfl_xor(acc.x, m, 64);
        acc.y += __shfl_xor(acc.y, m, 64);
        acc.z += __shfl_xor(acc.z, m, 64);
        acc.w += __shfl_xor(acc.w, m, 64);
    }

    if (g == 0) {
        float dn = dinv[node];
        float4 bb = b4[fl];
        float4 o;
        o.x = bb.x + dn * acc.x;
        o.y = bb.y + dn * acc.y;
        o.z = bb.z + dn * acc.z;
        o.w = bb.w + dn * acc.w;
        agg4[(size_t)node * 16 + fl] = o;
    }
}

// ---------------- final: out = relu(agg) @ Wl + bl ----------------

__global__ __launch_bounds__(256) void final_k(const float* __restrict__ agg,
                                               const float* __restrict__ Wl,
                                               const float* __restrict__ bl,
                                               float* __restrict__ out) {
    __shared__ float Ws[HIDDEN * N_CLASSES];
    __shared__ float hs[16][HIDDEN + 1];
    int tid = threadIdx.x;

    if (tid < HIDDEN * N_CLASSES / 4) ((float4*)Ws)[tid] = ((const float4*)Wl)[tid];

    int row0 = blockIdx.x * 16;
    for (int i = tid; i < 16 * HIDDEN; i += 256) {
        int rr = i >> 6;
        int kk = i & 63;
        hs[rr][kk] = fmaxf(agg[(size_t)(row0 + rr) * HIDDEN + kk], 0.0f);
    }
    __syncthreads();

    int col = tid & 15;
    int r = tid >> 4;
    float acc = bl[col];
    #pragma unroll
    for (int k = 0; k < HIDDEN; ++k)
        acc += hs[r][k] * Ws[k * N_CLASSES + col];
    out[(size_t)(row0 + r) * N_CLASSES + col] = acc;
}

// ---------------- launch ----------------

extern "C" void kernel_launch(void* const* d_in, const int* in_sizes, int n_in,
                              void* d_out, int out_size, void* d_ws, size_t ws_size,
                              hipStream_t stream) {
    const float* x  = (const float*)d_in[0];
    const int*   ei = (const int*)d_in[1];
    const float* W1 = (const float*)d_in[2];
    const float* b1 = (const float*)d_in[3];
    const float* W2 = (const float*)d_in[4];
    const float* b2 = (const float*)d_in[5];
    const float* Wl = (const float*)d_in[6];
    const float* bl = (const float*)d_in[7];
    float* out = (float*)d_out;

    const int* src = ei;
    const int* dst = ei + N_EDGES;

    float* hws     = (float*)d_ws;                            // N*64
    float* agg     = hws + (size_t)N_NODES * HIDDEN;          // N*64
    int2*  pairs   = (int2*)agg;                              // aliases agg (dead before pull writes agg)
    int*   csr_src = (int*)(agg + (size_t)N_NODES * HIDDEN);  // E
    int*   deg     = csr_src + N_EDGES;                       // N
    float* dinv    = (float*)(deg + N_NODES);                 // N
    int*   row_ptr = (int*)(dinv + N_NODES);                  // N+4
    int*   blk_sum = row_ptr + N_NODES + 4;                   // 200
    int*   blk_off = blk_sum + 200;                           // 200
    int*   bcur    = blk_off + 200;                           // 200

    // --- degree + row_ptr ---
    zero_deg_k<<<(N_NODES + 255) / 256, 256, 0, stream>>>(deg);
    hist_sliced_k<<<NCHUNK * NSLICE, 256, 0, stream>>>(dst, deg);
    dinv_k<<<(N_NODES + 255) / 256, 256, 0, stream>>>(deg, dinv);
    chunk_sum_k<<<NB, 256, 0, stream>>>(deg, blk_sum);
    scan_blocks_k<<<1, 256, 0, stream>>>(blk_sum, blk_off, row_ptr);
    rowptr_k<<<NB, 256, 0, stream>>>(deg, blk_off, row_ptr);
    bcur_init_k<<<1, 256, 0, stream>>>(row_ptr, bcur);

    // --- CSR fill ---
    coarse_k<<<NCB, 256, 0, stream>>>(src, dst, bcur, pairs);
    fine_k<<<NBUK, 256, 0, stream>>>(pairs, row_ptr, csr_src);

    // --- layer 1 ---
    gemm1_tiled_k<<<GBLK, 256, 0, stream>>>(x, W1, dinv, hws);
    pull_k<<<(N_NODES * 64 + 255) / 256, 256, 0, stream>>>(row_ptr, csr_src, dinv,
                                                           (const float4*)hws,
                                                           (const float4*)b1,
                                                           (float4*)agg);

    // --- layer 2 ---
    gemm2_tiled_k<<<GBLK, 256, 0, stream>>>(agg, W2, dinv, hws);
    pull_k<<<(N_NODES * 64 + 255) / 256, 256, 0, stream>>>(row_ptr, csr_src, dinv,
                                                           (const float4*)hws,
                                                           (const float4*)b2,
                                                           (float4*)agg);

    // --- classifier head ---
    final_k<<<N_NODES / 16, 256, 0, stream>>>(agg, Wl, bl, out);
}

// Round 7
// 398.946 us; speedup vs baseline: 1.0594x; 1.0594x over previous
//
#include <hip/hip_runtime.h>
#include <math.h>

#define N_NODES 100000
#define N_EDGES 1600000
#define IN_FEAT 128
#define HIDDEN 64
#define N_CLASSES 16

#define CHUNK 512
#define NB ((N_NODES + CHUNK - 1) / CHUNK)  // 196

#define NSLICE 8
#define SLICE_SZ ((N_NODES + NSLICE - 1) / NSLICE)  // 12500
#define EPB 1024
#define NCHUNK ((N_EDGES + EPB - 1) / EPB)

#define TM 64
#define GBLK ((N_NODES + TM - 1) / TM)  // 1563

#define NBUK 196                        // buckets of 512 nodes (dst>>9)
#define CB 4096                         // edges per coarse block
#define NCB ((N_EDGES + CB - 1) / CB)   // 391

// ---------------- degree ----------------

__global__ void zero_deg_k(int* __restrict__ deg) {
    int i = blockIdx.x * blockDim.x + threadIdx.x;
    if (i < N_NODES) deg[i] = 0;
}

__global__ __launch_bounds__(256) void hist_sliced_k(const int* __restrict__ dst,
                                                     int* __restrict__ deg) {
    int slice = blockIdx.x & (NSLICE - 1);
    int chunk = blockIdx.x >> 3;
    int lo = slice * SLICE_SZ;
    int hi = lo + SLICE_SZ;
    int base = chunk * EPB + threadIdx.x * 4;
    if (base >= N_EDGES) return;
    int4 d4 = ((const int4*)dst)[base >> 2];
    if (d4.x >= lo && d4.x < hi) atomicAdd(&deg[d4.x], 1);
    if (d4.y >= lo && d4.y < hi) atomicAdd(&deg[d4.y], 1);
    if (d4.z >= lo && d4.z < hi) atomicAdd(&deg[d4.z], 1);
    if (d4.w >= lo && d4.w < hi) atomicAdd(&deg[d4.w], 1);
}

__global__ void dinv_k(const int* __restrict__ deg, float* __restrict__ dinv) {
    int i = blockIdx.x * blockDim.x + threadIdx.x;
    if (i < N_NODES) dinv[i] = 1.0f / sqrtf((float)(deg[i] + 1));
}

// ---------------- row_ptr (hierarchical scan) ----------------

__global__ __launch_bounds__(256) void chunk_sum_k(const int* __restrict__ deg,
                                                   int* __restrict__ blk_sum) {
    __shared__ int sm[256];
    int b = blockIdx.x, t = threadIdx.x;
    int i0 = b * CHUNK + t;
    int v = 0;
    if (i0 < N_NODES) v += deg[i0];
    if (i0 + 256 < N_NODES) v += deg[i0 + 256];
    sm[t] = v;
    __syncthreads();
    for (int s = 128; s > 0; s >>= 1) {
        if (t < s) sm[t] += sm[t + s];
        __syncthreads();
    }
    if (t == 0) blk_sum[b] = sm[0];
}

__global__ __launch_bounds__(256) void scan_blocks_k(const int* __restrict__ blk_sum,
                                                     int* __restrict__ blk_off,
                                                     int* __restrict__ row_ptr) {
    __shared__ int sm[256];
    int t = threadIdx.x;
    int v = (t < NB) ? blk_sum[t] : 0;
    sm[t] = v;
    __syncthreads();
    for (int s = 1; s < 256; s <<= 1) {
        int add = (t >= s) ? sm[t - s] : 0;
        __syncthreads();
        sm[t] += add;
        __syncthreads();
    }
    if (t < NB) blk_off[t] = sm[t] - v;
    if (t == 0) row_ptr[N_NODES] = N_EDGES;
}

__global__ __launch_bounds__(256) void rowptr_k(const int* __restrict__ deg,
                                                const int* __restrict__ blk_off,
                                                int* __restrict__ row_ptr) {
    __shared__ int pair[256];
    int b = blockIdx.x, t = threadIdx.x;
    int i0 = b * CHUNK + 2 * t;
    int d0 = (i0 < N_NODES) ? deg[i0] : 0;
    int d1 = (i0 + 1 < N_NODES) ? deg[i0 + 1] : 0;
    int p = d0 + d1;
    pair[t] = p;
    __syncthreads();
    for (int s = 1; s < 256; s <<= 1) {
        int add = (t >= s) ? pair[t - s] : 0;
        __syncthreads();
        pair[t] += add;
        __syncthreads();
    }
    int excl = pair[t] - p + blk_off[b];
    if (i0 < N_NODES)     row_ptr[i0]     = excl;
    if (i0 + 1 < N_NODES) row_ptr[i0 + 1] = excl + d0;
}

__global__ void bcur_init_k(const int* __restrict__ row_ptr, int* __restrict__ bcur) {
    int b = blockIdx.x * blockDim.x + threadIdx.x;
    if (b < NBUK) bcur[b] = row_ptr[b * 512];
}

// ---------------- coarse partition: group edges by 512-node bucket ----------------

__global__ __launch_bounds__(256) void coarse_k(const int* __restrict__ src,
                                                const int* __restrict__ dst,
                                                int* __restrict__ bcur,
                                                int2* __restrict__ pairs) {
    __shared__ int hist[NBUK + 4], loff[NBUK + 4], cur[NBUK + 4], gbase[NBUK + 4];
    __shared__ int sc[256];
    __shared__ int2 stage[CB];  // 32 KB
    int tid = threadIdx.x;
    int eb = blockIdx.x * CB;
    int nvalid = N_EDGES - eb;
    if (nvalid > CB) nvalid = CB;

    if (tid < NBUK) hist[tid] = 0;
    __syncthreads();

    int4 s4[4], d4[4];
    #pragma unroll
    for (int q = 0; q < 4; ++q) {
        int e4 = (eb >> 2) + tid + q * 256;
        if (e4 * 4 < N_EDGES) {
            s4[q] = ((const int4*)src)[e4];
            d4[q] = ((const int4*)dst)[e4];
        } else {
            d4[q] = make_int4(-1, -1, -1, -1);
            s4[q] = make_int4(0, 0, 0, 0);
        }
    }
    #pragma unroll
    for (int q = 0; q < 4; ++q) {
        if (d4[q].x >= 0) {
            atomicAdd(&hist[d4[q].x >> 9], 1);
            atomicAdd(&hist[d4[q].y >> 9], 1);
            atomicAdd(&hist[d4[q].z >> 9], 1);
            atomicAdd(&hist[d4[q].w >> 9], 1);
        }
    }
    __syncthreads();

    int v = (tid < NBUK) ? hist[tid] : 0;
    sc[tid] = v;
    __syncthreads();
    for (int s = 1; s < 256; s <<= 1) {
        int add = (tid >= s) ? sc[tid - s] : 0;
        __syncthreads();
        sc[tid] += add;
        __syncthreads();
    }
    if (tid < NBUK) {
        int excl = sc[tid] - v;
        loff[tid] = excl;
        cur[tid] = excl;
        gbase[tid] = atomicAdd(&bcur[tid], v);
    }
    __syncthreads();

    #pragma unroll
    for (int q = 0; q < 4; ++q) {
        if (d4[q].x >= 0) {
            int b, r;
            b = d4[q].x >> 9; r = atomicAdd(&cur[b], 1); stage[r] = make_int2(s4[q].x, d4[q].x);
            b = d4[q].y >> 9; r = atomicAdd(&cur[b], 1); stage[r] = make_int2(s4[q].y, d4[q].y);
            b = d4[q].z >> 9; r = atomicAdd(&cur[b], 1); stage[r] = make_int2(s4[q].z, d4[q].z);
            b = d4[q].w >> 9; r = atomicAdd(&cur[b], 1); stage[r] = make_int2(s4[q].w, d4[q].w);
        }
    }
    __syncthreads();

    for (int i = tid; i < nvalid; i += 256) {
        int2 p = stage[i];
        int b = p.y >> 9;
        pairs[gbase[b] + (i - loff[b])] = p;
    }
}

// ---------------- fine fill: per-bucket CSR placement ----------------

__global__ __launch_bounds__(256) void fine_k(const int2* __restrict__ pairs,
                                              const int* __restrict__ row_ptr,
                                              int* __restrict__ csr_src) {
    __shared__ int cur[512];
    int b = blockIdx.x;
    int node0 = b * 512;
    int nn = N_NODES - node0;
    if (nn > 512) nn = 512;
    int tid = threadIdx.x;
    for (int j = tid; j < nn; j += 256) cur[j] = row_ptr[node0 + j];
    __syncthreads();
    int e0 = row_ptr[node0];
    int e1 = row_ptr[node0 + nn];
    for (int e = e0 + tid; e < e1; e += 256) {
        int2 p = pairs[e];
        int pos = atomicAdd(&cur[p.y - node0], 1);
        csr_src[pos] = p.x;
    }
}

// ---------------- register-tiled GEMM 1: hws = (x @ W1) * dinv[row] ----------------

__global__ __launch_bounds__(256) void gemm1_tiled_k(const float* __restrict__ x,
                                                     const float* __restrict__ W,
                                                     const float* __restrict__ dinv,
                                                     float* __restrict__ hws) {
    __shared__ float Ws[64][64];
    __shared__ float xt[64][68];
    int tid = threadIdx.x;
    int row0 = blockIdx.x * TM;
    int rgrp4 = (tid >> 4) * 4;
    int cgrp4 = (tid & 15) * 4;

    float acc[4][4];
    #pragma unroll
    for (int r = 0; r < 4; ++r)
        #pragma unroll
        for (int c = 0; c < 4; ++c) acc[r][c] = 0.0f;

    for (int k0 = 0; k0 < IN_FEAT; k0 += 64) {
        #pragma unroll
        for (int i = 0; i < 4; ++i) {
            int f4 = tid + i * 256;
            int kk = f4 >> 4, c4 = (f4 & 15) * 4;
            *(float4*)&Ws[kk][c4] = *(const float4*)&W[(size_t)(k0 + kk) * HIDDEN + c4];
        }
        #pragma unroll
        for (int i = 0; i < 4; ++i) {
            int f4 = tid + i * 256;
            int rr = f4 >> 4, kq = (f4 & 15) * 4;
            int row = row0 + rr;
            if (row >= N_NODES) row = N_NODES - 1;
            float4 v = *(const float4*)&x[(size_t)row * IN_FEAT + k0 + kq];
            xt[kq + 0][rr] = v.x; xt[kq + 1][rr] = v.y;
            xt[kq + 2][rr] = v.z; xt[kq + 3][rr] = v.w;
        }
        __syncthreads();

        #pragma unroll 16
        for (int kk = 0; kk < 64; ++kk) {
            float4 a = *(const float4*)&xt[kk][rgrp4];
            float4 b = *(const float4*)&Ws[kk][cgrp4];
            acc[0][0] += a.x * b.x; acc[0][1] += a.x * b.y; acc[0][2] += a.x * b.z; acc[0][3] += a.x * b.w;
            acc[1][0] += a.y * b.x; acc[1][1] += a.y * b.y; acc[1][2] += a.y * b.z; acc[1][3] += a.y * b.w;
            acc[2][0] += a.z * b.x; acc[2][1] += a.z * b.y; acc[2][2] += a.z * b.z; acc[2][3] += a.z * b.w;
            acc[3][0] += a.w * b.x; acc[3][1] += a.w * b.y; acc[3][2] += a.w * b.z; acc[3][3] += a.w * b.w;
        }
        __syncthreads();
    }

    #pragma unroll
    for (int r = 0; r < 4; ++r) {
        int row = row0 + rgrp4 + r;
        if (row < N_NODES) {
            float dn = dinv[row];
            float4 o = make_float4(acc[r][0] * dn, acc[r][1] * dn, acc[r][2] * dn, acc[r][3] * dn);
            *(float4*)&hws[(size_t)row * HIDDEN + cgrp4] = o;
        }
    }
}

// ---------------- register-tiled GEMM 2: hws = (relu(agg) @ W2) * dinv[row] ----------------

__global__ __launch_bounds__(256) void gemm2_tiled_k(const float* __restrict__ agg,
                                                     const float* __restrict__ W,
                                                     const float* __restrict__ dinv,
                                                     float* __restrict__ hws) {
    __shared__ float Ws[64][64];
    __shared__ float xt[64][68];
    int tid = threadIdx.x;
    int row0 = blockIdx.x * TM;
    int rgrp4 = (tid >> 4) * 4;
    int cgrp4 = (tid & 15) * 4;

    #pragma unroll
    for (int i = 0; i < 4; ++i) {
        int f4 = tid + i * 256;
        int kk = f4 >> 4, c4 = (f4 & 15) * 4;
        *(float4*)&Ws[kk][c4] = *(const float4*)&W[(size_t)kk * HIDDEN + c4];
    }
    #pragma unroll
    for (int i = 0; i < 4; ++i) {
        int f4 = tid + i * 256;
        int rr = f4 >> 4, kq = (f4 & 15) * 4;
        int row = row0 + rr;
        if (row >= N_NODES) row = N_NODES - 1;
        float4 v = *(const float4*)&agg[(size_t)row * HIDDEN + kq];
        xt[kq + 0][rr] = fmaxf(v.x, 0.f); xt[kq + 1][rr] = fmaxf(v.y, 0.f);
        xt[kq + 2][rr] = fmaxf(v.z, 0.f); xt[kq + 3][rr] = fmaxf(v.w, 0.f);
    }
    __syncthreads();

    float acc[4][4];
    #pragma unroll
    for (int r = 0; r < 4; ++r)
        #pragma unroll
        for (int c = 0; c < 4; ++c) acc[r][c] = 0.0f;

    #pragma unroll 16
    for (int kk = 0; kk < 64; ++kk) {
        float4 a = *(const float4*)&xt[kk][rgrp4];
        float4 b = *(const float4*)&Ws[kk][cgrp4];
        acc[0][0] += a.x * b.x; acc[0][1] += a.x * b.y; acc[0][2] += a.x * b.z; acc[0][3] += a.x * b.w;
        acc[1][0] += a.y * b.x; acc[1][1] += a.y * b.y; acc[1][2] += a.y * b.z; acc[1][3] += a.y * b.w;
        acc[2][0] += a.z * b.x; acc[2][1] += a.z * b.y; acc[2][2] += a.z * b.z; acc[2][3] += a.z * b.w;
        acc[3][0] += a.w * b.x; acc[3][1] += a.w * b.y; acc[3][2] += a.w * b.z; acc[3][3] += a.w * b.w;
    }

    #pragma unroll
    for (int r = 0; r < 4; ++r) {
        int row = row0 + rgrp4 + r;
        if (row < N_NODES) {
            float dn = dinv[row];
            float4 o = make_float4(acc[r][0] * dn, acc[r][1] * dn, acc[r][2] * dn, acc[r][3] * dn);
            *(float4*)&hws[(size_t)row * HIDDEN + cgrp4] = o;
        }
    }
}

// ---------------- CSR pull: agg[d] = b + dinv[d]*(hws[d] + sum_in hws[s]) ----------------
// one wave per node, lane = channel (64 floats/row). Edge indices are wave-uniform ->
// scalar loads; main loops are guard-free so 8 (then 4) 256B gathers stay in flight.

__global__ __launch_bounds__(256) void pull_k(const int* __restrict__ row_ptr,
                                              const int* __restrict__ csr_src,
                                              const float* __restrict__ dinv,
                                              const float* __restrict__ hws,
                                              const float* __restrict__ b,
                                              float* __restrict__ agg) {
    int node = (blockIdx.x * 256 + threadIdx.x) >> 6;
    int lane = threadIdx.x & 63;
    if (node >= N_NODES) return;

    int start = row_ptr[node];
    int end   = row_ptr[node + 1];

    float a0 = hws[(size_t)node * HIDDEN + lane];  // self-loop term
    float a1 = 0.f, a2 = 0.f, a3 = 0.f, a4 = 0.f, a5 = 0.f, a6 = 0.f, a7 = 0.f;

    int i = start;
    for (; i + 8 <= end; i += 8) {
        int s0 = csr_src[i + 0]; int s1 = csr_src[i + 1];
        int s2 = csr_src[i + 2]; int s3 = csr_src[i + 3];
        int s4 = csr_src[i + 4]; int s5 = csr_src[i + 5];
        int s6 = csr_src[i + 6]; int s7 = csr_src[i + 7];
        a0 += hws[(size_t)s0 * HIDDEN + lane];
        a1 += hws[(size_t)s1 * HIDDEN + lane];
        a2 += hws[(size_t)s2 * HIDDEN + lane];
        a3 += hws[(size_t)s3 * HIDDEN + lane];
        a4 += hws[(size_t)s4 * HIDDEN + lane];
        a5 += hws[(size_t)s5 * HIDDEN + lane];
        a6 += hws[(size_t)s6 * HIDDEN + lane];
        a7 += hws[(size_t)s7 * HIDDEN + lane];
    }
    for (; i + 4 <= end; i += 4) {
        int s0 = csr_src[i + 0]; int s1 = csr_src[i + 1];
        int s2 = csr_src[i + 2]; int s3 = csr_src[i + 3];
        a0 += hws[(size_t)s0 * HIDDEN + lane];
        a1 += hws[(size_t)s1 * HIDDEN + lane];
        a2 += hws[(size_t)s2 * HIDDEN + lane];
        a3 += hws[(size_t)s3 * HIDDEN + lane];
    }
    for (; i < end; ++i) {
        int s = csr_src[i];
        a0 += hws[(size_t)s * HIDDEN + lane];
    }

    float sum = ((a0 + a1) + (a2 + a3)) + ((a4 + a5) + (a6 + a7));
    agg[(size_t)node * HIDDEN + lane] = b[lane] + dinv[node] * sum;
}

// ---------------- final: out = relu(agg) @ Wl + bl ----------------

__global__ __launch_bounds__(256) void final_k(const float* __restrict__ agg,
                                               const float* __restrict__ Wl,
                                               const float* __restrict__ bl,
                                               float* __restrict__ out) {
    __shared__ float Ws[HIDDEN * N_CLASSES];
    __shared__ float hs[16][HIDDEN + 1];
    int tid = threadIdx.x;

    if (tid < HIDDEN * N_CLASSES / 4) ((float4*)Ws)[tid] = ((const float4*)Wl)[tid];

    int row0 = blockIdx.x * 16;
    for (int i = tid; i < 16 * HIDDEN; i += 256) {
        int rr = i >> 6;
        int kk = i & 63;
        hs[rr][kk] = fmaxf(agg[(size_t)(row0 + rr) * HIDDEN + kk], 0.0f);
    }
    __syncthreads();

    int col = tid & 15;
    int r = tid >> 4;
    float acc = bl[col];
    #pragma unroll
    for (int k = 0; k < HIDDEN; ++k)
        acc += hs[r][k] * Ws[k * N_CLASSES + col];
    out[(size_t)(row0 + r) * N_CLASSES + col] = acc;
}

// ---------------- launch ----------------

extern "C" void kernel_launch(void* const* d_in, const int* in_sizes, int n_in,
                              void* d_out, int out_size, void* d_ws, size_t ws_size,
                              hipStream_t stream) {
    const float* x  = (const float*)d_in[0];
    const int*   ei = (const int*)d_in[1];
    const float* W1 = (const float*)d_in[2];
    const float* b1 = (const float*)d_in[3];
    const float* W2 = (const float*)d_in[4];
    const float* b2 = (const float*)d_in[5];
    const float* Wl = (const float*)d_in[6];
    const float* bl = (const float*)d_in[7];
    float* out = (float*)d_out;

    const int* src = ei;
    const int* dst = ei + N_EDGES;

    float* hws     = (float*)d_ws;                            // N*64
    float* agg     = hws + (size_t)N_NODES * HIDDEN;          // N*64
    int2*  pairs   = (int2*)agg;                              // aliases agg (dead before pull writes agg)
    int*   csr_src = (int*)(agg + (size_t)N_NODES * HIDDEN);  // E
    int*   deg     = csr_src + N_EDGES;                       // N
    float* dinv    = (float*)(deg + N_NODES);                 // N
    int*   row_ptr = (int*)(dinv + N_NODES);                  // N+4
    int*   blk_sum = row_ptr + N_NODES + 4;                   // 200
    int*   blk_off = blk_sum + 200;                           // 200
    int*   bcur    = blk_off + 200;                           // 200

    // --- degree + row_ptr ---
    zero_deg_k<<<(N_NODES + 255) / 256, 256, 0, stream>>>(deg);
    hist_sliced_k<<<NCHUNK * NSLICE, 256, 0, stream>>>(dst, deg);
    dinv_k<<<(N_NODES + 255) / 256, 256, 0, stream>>>(deg, dinv);
    chunk_sum_k<<<NB, 256, 0, stream>>>(deg, blk_sum);
    scan_blocks_k<<<1, 256, 0, stream>>>(blk_sum, blk_off, row_ptr);
    rowptr_k<<<NB, 256, 0, stream>>>(deg, blk_off, row_ptr);
    bcur_init_k<<<1, 256, 0, stream>>>(row_ptr, bcur);

    // --- CSR fill ---
    coarse_k<<<NCB, 256, 0, stream>>>(src, dst, bcur, pairs);
    fine_k<<<NBUK, 256, 0, stream>>>(pairs, row_ptr, csr_src);

    // --- layer 1 ---
    gemm1_tiled_k<<<GBLK, 256, 0, stream>>>(x, W1, dinv, hws);
    pull_k<<<(N_NODES * 64 + 255) / 256, 256, 0, stream>>>(row_ptr, csr_src, dinv,
                                                           hws, b1, agg);

    // --- layer 2 ---
    gemm2_tiled_k<<<GBLK, 256, 0, stream>>>(agg, W2, dinv, hws);
    pull_k<<<(N_NODES * 64 + 255) / 256, 256, 0, stream>>>(row_ptr, csr_src, dinv,
                                                           hws, b2, agg);

    // --- classifier head ---
    final_k<<<N_NODES / 16, 256, 0, stream>>>(agg, Wl, bl, out);
}

// Round 8
// 376.544 us; speedup vs baseline: 1.1225x; 1.0595x over previous
//
#include <hip/hip_runtime.h>
#include <math.h>

#define N_NODES 100000
#define N_EDGES 1600000
#define IN_FEAT 128
#define HIDDEN 64
#define N_CLASSES 16

#define TM 64
#define GBLK ((N_NODES + TM - 1) / TM)  // 1563

#define NBUK 196                        // buckets of 512 nodes (dst>>9)
#define CB 4096                         // edges per coarse block
#define NCB ((N_EDGES + CB - 1) / CB)   // 391
#define EPB 1024                        // edges per bukhist block
#define NHB ((N_EDGES + EPB - 1) / EPB) // 1563

// ---------------- bucket histogram (LDS, tiny global flush) ----------------

__global__ void zero_buk_k(int* __restrict__ buk_cnt) {
    if (threadIdx.x < NBUK + 4) buk_cnt[threadIdx.x] = 0;
}

__global__ __launch_bounds__(256) void bukhist_k(const int* __restrict__ dst,
                                                 int* __restrict__ buk_cnt) {
    __shared__ int hist[NBUK + 4];
    int tid = threadIdx.x;
    if (tid < NBUK) hist[tid] = 0;
    __syncthreads();
    int base = blockIdx.x * EPB + tid * 4;
    if (base < N_EDGES) {  // N_EDGES % 4 == 0
        int4 d4 = ((const int4*)dst)[base >> 2];
        atomicAdd(&hist[d4.x >> 9], 1);
        atomicAdd(&hist[d4.y >> 9], 1);
        atomicAdd(&hist[d4.z >> 9], 1);
        atomicAdd(&hist[d4.w >> 9], 1);
    }
    __syncthreads();
    if (tid < NBUK && hist[tid] != 0) atomicAdd(&buk_cnt[tid], hist[tid]);
}

// scan 196 bucket counts -> buk_off (exclusive), init bcur
__global__ __launch_bounds__(256) void buk_scan_k(const int* __restrict__ buk_cnt,
                                                  int* __restrict__ buk_off,
                                                  int* __restrict__ bcur) {
    __shared__ int sm[256];
    int t = threadIdx.x;
    int v = (t < NBUK) ? buk_cnt[t] : 0;
    sm[t] = v;
    __syncthreads();
    for (int s = 1; s < 256; s <<= 1) {
        int add = (t >= s) ? sm[t - s] : 0;
        __syncthreads();
        sm[t] += add;
        __syncthreads();
    }
    if (t < NBUK) {
        int excl = sm[t] - v;
        buk_off[t] = excl;
        bcur[t] = excl;
    }
    if (t == 0) buk_off[NBUK] = N_EDGES;
}

// ---------------- coarse partition: group edges by 512-node bucket ----------------

__global__ __launch_bounds__(256) void coarse_k(const int* __restrict__ src,
                                                const int* __restrict__ dst,
                                                int* __restrict__ bcur,
                                                int2* __restrict__ pairs) {
    __shared__ int hist[NBUK + 4], loff[NBUK + 4], cur[NBUK + 4], gbase[NBUK + 4];
    __shared__ int sc[256];
    __shared__ int2 stage[CB];  // 32 KB
    int tid = threadIdx.x;
    int eb = blockIdx.x * CB;
    int nvalid = N_EDGES - eb;
    if (nvalid > CB) nvalid = CB;

    if (tid < NBUK) hist[tid] = 0;
    __syncthreads();

    int4 s4[4], d4[4];
    #pragma unroll
    for (int q = 0; q < 4; ++q) {
        int e4 = (eb >> 2) + tid + q * 256;
        if (e4 * 4 < N_EDGES) {
            s4[q] = ((const int4*)src)[e4];
            d4[q] = ((const int4*)dst)[e4];
        } else {
            d4[q] = make_int4(-1, -1, -1, -1);
            s4[q] = make_int4(0, 0, 0, 0);
        }
    }
    #pragma unroll
    for (int q = 0; q < 4; ++q) {
        if (d4[q].x >= 0) {
            atomicAdd(&hist[d4[q].x >> 9], 1);
            atomicAdd(&hist[d4[q].y >> 9], 1);
            atomicAdd(&hist[d4[q].z >> 9], 1);
            atomicAdd(&hist[d4[q].w >> 9], 1);
        }
    }
    __syncthreads();

    int v = (tid < NBUK) ? hist[tid] : 0;
    sc[tid] = v;
    __syncthreads();
    for (int s = 1; s < 256; s <<= 1) {
        int add = (tid >= s) ? sc[tid - s] : 0;
        __syncthreads();
        sc[tid] += add;
        __syncthreads();
    }
    if (tid < NBUK) {
        int excl = sc[tid] - v;
        loff[tid] = excl;
        cur[tid] = excl;
        gbase[tid] = atomicAdd(&bcur[tid], v);
    }
    __syncthreads();

    #pragma unroll
    for (int q = 0; q < 4; ++q) {
        if (d4[q].x >= 0) {
            int b, r;
            b = d4[q].x >> 9; r = atomicAdd(&cur[b], 1); stage[r] = make_int2(s4[q].x, d4[q].x);
            b = d4[q].y >> 9; r = atomicAdd(&cur[b], 1); stage[r] = make_int2(s4[q].y, d4[q].y);
            b = d4[q].z >> 9; r = atomicAdd(&cur[b], 1); stage[r] = make_int2(s4[q].z, d4[q].z);
            b = d4[q].w >> 9; r = atomicAdd(&cur[b], 1); stage[r] = make_int2(s4[q].w, d4[q].w);
        }
    }
    __syncthreads();

    for (int i = tid; i < nvalid; i += 256) {
        int2 p = stage[i];
        int b = p.y >> 9;
        pairs[gbase[b] + (i - loff[b])] = p;
    }
}

// ---------------- fine: per-bucket degree count (LDS) + dinv + row_ptr + placement ----------------
// One block owns one 512-node bucket. Degrees only ever counted in LDS; dinv and
// row_ptr written directly; csr_src scatter confined to a ~32KB block-local region.

__global__ __launch_bounds__(256) void fine2_k(const int2* __restrict__ pairs,
                                               const int* __restrict__ buk_off,
                                               int* __restrict__ csr_src,
                                               int* __restrict__ row_ptr,
                                               float* __restrict__ dinv) {
    __shared__ int cnt[512];
    __shared__ int psc[256];
    __shared__ int cur[512];
    int b = blockIdx.x;
    int node0 = b * 512;
    int nn = N_NODES - node0;
    if (nn > 512) nn = 512;
    int tid = threadIdx.x;

    cnt[tid] = 0; cnt[tid + 256] = 0;
    __syncthreads();

    int e0 = buk_off[b];
    int e1 = buk_off[b + 1];

    // pass 1: count degrees in LDS
    for (int e = e0 + tid; e < e1; e += 256)
        atomicAdd(&cnt[pairs[e].y - node0], 1);
    __syncthreads();

    // scan 512 counts with 256 threads (2 elements/thread)
    int c0 = cnt[2 * tid], c1 = cnt[2 * tid + 1];
    int p = c0 + c1;
    psc[tid] = p;
    __syncthreads();
    for (int s = 1; s < 256; s <<= 1) {
        int add = (tid >= s) ? psc[tid - s] : 0;
        __syncthreads();
        psc[tid] += add;
        __syncthreads();
    }
    int excl = psc[tid] - p;
    int g0 = e0 + excl;
    int g1 = g0 + c0;
    cur[2 * tid] = g0;
    cur[2 * tid + 1] = g1;
    if (2 * tid < nn) {
        row_ptr[node0 + 2 * tid] = g0;
        dinv[node0 + 2 * tid] = 1.0f / sqrtf((float)(c0 + 1));
    }
    if (2 * tid + 1 < nn) {
        row_ptr[node0 + 2 * tid + 1] = g1;
        dinv[node0 + 2 * tid + 1] = 1.0f / sqrtf((float)(c1 + 1));
    }
    if (b == NBUK - 1 && tid == 0) row_ptr[N_NODES] = N_EDGES;
    __syncthreads();

    // pass 2: place edges
    for (int e = e0 + tid; e < e1; e += 256) {
        int2 pr = pairs[e];
        int pos = atomicAdd(&cur[pr.y - node0], 1);
        csr_src[pos] = pr.x;
    }
}

// ---------------- register-tiled GEMM 1: hws = (x @ W1) * dinv[row] ----------------

__global__ __launch_bounds__(256) void gemm1_tiled_k(const float* __restrict__ x,
                                                     const float* __restrict__ W,
                                                     const float* __restrict__ dinv,
                                                     float* __restrict__ hws) {
    __shared__ float Ws[64][64];
    __shared__ float xt[64][68];
    int tid = threadIdx.x;
    int row0 = blockIdx.x * TM;
    int rgrp4 = (tid >> 4) * 4;
    int cgrp4 = (tid & 15) * 4;

    float acc[4][4];
    #pragma unroll
    for (int r = 0; r < 4; ++r)
        #pragma unroll
        for (int c = 0; c < 4; ++c) acc[r][c] = 0.0f;

    for (int k0 = 0; k0 < IN_FEAT; k0 += 64) {
        #pragma unroll
        for (int i = 0; i < 4; ++i) {
            int f4 = tid + i * 256;
            int kk = f4 >> 4, c4 = (f4 & 15) * 4;
            *(float4*)&Ws[kk][c4] = *(const float4*)&W[(size_t)(k0 + kk) * HIDDEN + c4];
        }
        #pragma unroll
        for (int i = 0; i < 4; ++i) {
            int f4 = tid + i * 256;
            int rr = f4 >> 4, kq = (f4 & 15) * 4;
            int row = row0 + rr;
            if (row >= N_NODES) row = N_NODES - 1;
            float4 v = *(const float4*)&x[(size_t)row * IN_FEAT + k0 + kq];
            xt[kq + 0][rr] = v.x; xt[kq + 1][rr] = v.y;
            xt[kq + 2][rr] = v.z; xt[kq + 3][rr] = v.w;
        }
        __syncthreads();

        #pragma unroll 16
        for (int kk = 0; kk < 64; ++kk) {
            float4 a = *(const float4*)&xt[kk][rgrp4];
            float4 b = *(const float4*)&Ws[kk][cgrp4];
            acc[0][0] += a.x * b.x; acc[0][1] += a.x * b.y; acc[0][2] += a.x * b.z; acc[0][3] += a.x * b.w;
            acc[1][0] += a.y * b.x; acc[1][1] += a.y * b.y; acc[1][2] += a.y * b.z; acc[1][3] += a.y * b.w;
            acc[2][0] += a.z * b.x; acc[2][1] += a.z * b.y; acc[2][2] += a.z * b.z; acc[2][3] += a.z * b.w;
            acc[3][0] += a.w * b.x; acc[3][1] += a.w * b.y; acc[3][2] += a.w * b.z; acc[3][3] += a.w * b.w;
        }
        __syncthreads();
    }

    #pragma unroll
    for (int r = 0; r < 4; ++r) {
        int row = row0 + rgrp4 + r;
        if (row < N_NODES) {
            float dn = dinv[row];
            float4 o = make_float4(acc[r][0] * dn, acc[r][1] * dn, acc[r][2] * dn, acc[r][3] * dn);
            *(float4*)&hws[(size_t)row * HIDDEN + cgrp4] = o;
        }
    }
}

// ---------------- register-tiled GEMM 2: hws = (relu(agg) @ W2) * dinv[row] ----------------

__global__ __launch_bounds__(256) void gemm2_tiled_k(const float* __restrict__ agg,
                                                     const float* __restrict__ W,
                                                     const float* __restrict__ dinv,
                                                     float* __restrict__ hws) {
    __shared__ float Ws[64][64];
    __shared__ float xt[64][68];
    int tid = threadIdx.x;
    int row0 = blockIdx.x * TM;
    int rgrp4 = (tid >> 4) * 4;
    int cgrp4 = (tid & 15) * 4;

    #pragma unroll
    for (int i = 0; i < 4; ++i) {
        int f4 = tid + i * 256;
        int kk = f4 >> 4, c4 = (f4 & 15) * 4;
        *(float4*)&Ws[kk][c4] = *(const float4*)&W[(size_t)kk * HIDDEN + c4];
    }
    #pragma unroll
    for (int i = 0; i < 4; ++i) {
        int f4 = tid + i * 256;
        int rr = f4 >> 4, kq = (f4 & 15) * 4;
        int row = row0 + rr;
        if (row >= N_NODES) row = N_NODES - 1;
        float4 v = *(const float4*)&agg[(size_t)row * HIDDEN + kq];
        xt[kq + 0][rr] = fmaxf(v.x, 0.f); xt[kq + 1][rr] = fmaxf(v.y, 0.f);
        xt[kq + 2][rr] = fmaxf(v.z, 0.f); xt[kq + 3][rr] = fmaxf(v.w, 0.f);
    }
    __syncthreads();

    float acc[4][4];
    #pragma unroll
    for (int r = 0; r < 4; ++r)
        #pragma unroll
        for (int c = 0; c < 4; ++c) acc[r][c] = 0.0f;

    #pragma unroll 16
    for (int kk = 0; kk < 64; ++kk) {
        float4 a = *(const float4*)&xt[kk][rgrp4];
        float4 b = *(const float4*)&Ws[kk][cgrp4];
        acc[0][0] += a.x * b.x; acc[0][1] += a.x * b.y; acc[0][2] += a.x * b.z; acc[0][3] += a.x * b.w;
        acc[1][0] += a.y * b.x; acc[1][1] += a.y * b.y; acc[1][2] += a.y * b.z; acc[1][3] += a.y * b.w;
        acc[2][0] += a.z * b.x; acc[2][1] += a.z * b.y; acc[2][2] += a.z * b.z; acc[2][3] += a.z * b.w;
        acc[3][0] += a.w * b.x; acc[3][1] += a.w * b.y; acc[3][2] += a.w * b.z; acc[3][3] += a.w * b.w;
    }

    #pragma unroll
    for (int r = 0; r < 4; ++r) {
        int row = row0 + rgrp4 + r;
        if (row < N_NODES) {
            float dn = dinv[row];
            float4 o = make_float4(acc[r][0] * dn, acc[r][1] * dn, acc[r][2] * dn, acc[r][3] * dn);
            *(float4*)&hws[(size_t)row * HIDDEN + cgrp4] = o;
        }
    }
}

// ---------------- CSR pull: agg[d] = b + dinv[d]*(hws[d] + sum_in hws[s]) ----------------
// one wave per node, lane = channel. Wave-uniform edge indices -> scalar loads;
// guard-free 8/4-wide main loops keep gathers in flight.

__global__ __launch_bounds__(256) void pull_k(const int* __restrict__ row_ptr,
                                              const int* __restrict__ csr_src,
                                              const float* __restrict__ dinv,
                                              const float* __restrict__ hws,
                                              const float* __restrict__ b,
                                              float* __restrict__ agg) {
    int node = (blockIdx.x * 256 + threadIdx.x) >> 6;
    int lane = threadIdx.x & 63;
    if (node >= N_NODES) return;

    int start = row_ptr[node];
    int end   = row_ptr[node + 1];

    float a0 = hws[(size_t)node * HIDDEN + lane];  // self-loop term
    float a1 = 0.f, a2 = 0.f, a3 = 0.f, a4 = 0.f, a5 = 0.f, a6 = 0.f, a7 = 0.f;

    int i = start;
    for (; i + 8 <= end; i += 8) {
        int s0 = csr_src[i + 0]; int s1 = csr_src[i + 1];
        int s2 = csr_src[i + 2]; int s3 = csr_src[i + 3];
        int s4 = csr_src[i + 4]; int s5 = csr_src[i + 5];
        int s6 = csr_src[i + 6]; int s7 = csr_src[i + 7];
        a0 += hws[(size_t)s0 * HIDDEN + lane];
        a1 += hws[(size_t)s1 * HIDDEN + lane];
        a2 += hws[(size_t)s2 * HIDDEN + lane];
        a3 += hws[(size_t)s3 * HIDDEN + lane];
        a4 += hws[(size_t)s4 * HIDDEN + lane];
        a5 += hws[(size_t)s5 * HIDDEN + lane];
        a6 += hws[(size_t)s6 * HIDDEN + lane];
        a7 += hws[(size_t)s7 * HIDDEN + lane];
    }
    for (; i + 4 <= end; i += 4) {
        int s0 = csr_src[i + 0]; int s1 = csr_src[i + 1];
        int s2 = csr_src[i + 2]; int s3 = csr_src[i + 3];
        a0 += hws[(size_t)s0 * HIDDEN + lane];
        a1 += hws[(size_t)s1 * HIDDEN + lane];
        a2 += hws[(size_t)s2 * HIDDEN + lane];
        a3 += hws[(size_t)s3 * HIDDEN + lane];
    }
    for (; i < end; ++i) {
        int s = csr_src[i];
        a0 += hws[(size_t)s * HIDDEN + lane];
    }

    float sum = ((a0 + a1) + (a2 + a3)) + ((a4 + a5) + (a6 + a7));
    agg[(size_t)node * HIDDEN + lane] = b[lane] + dinv[node] * sum;
}

// ---------------- final: out = relu(agg) @ Wl + bl ----------------

__global__ __launch_bounds__(256) void final_k(const float* __restrict__ agg,
                                               const float* __restrict__ Wl,
                                               const float* __restrict__ bl,
                                               float* __restrict__ out) {
    __shared__ float Ws[HIDDEN * N_CLASSES];
    __shared__ float hs[16][HIDDEN + 1];
    int tid = threadIdx.x;

    if (tid < HIDDEN * N_CLASSES / 4) ((float4*)Ws)[tid] = ((const float4*)Wl)[tid];

    int row0 = blockIdx.x * 16;
    for (int i = tid; i < 16 * HIDDEN; i += 256) {
        int rr = i >> 6;
        int kk = i & 63;
        hs[rr][kk] = fmaxf(agg[(size_t)(row0 + rr) * HIDDEN + kk], 0.0f);
    }
    __syncthreads();

    int col = tid & 15;
    int r = tid >> 4;
    float acc = bl[col];
    #pragma unroll
    for (int k = 0; k < HIDDEN; ++k)
        acc += hs[r][k] * Ws[k * N_CLASSES + col];
    out[(size_t)(row0 + r) * N_CLASSES + col] = acc;
}

// ---------------- launch ----------------

extern "C" void kernel_launch(void* const* d_in, const int* in_sizes, int n_in,
                              void* d_out, int out_size, void* d_ws, size_t ws_size,
                              hipStream_t stream) {
    const float* x  = (const float*)d_in[0];
    const int*   ei = (const int*)d_in[1];
    const float* W1 = (const float*)d_in[2];
    const float* b1 = (const float*)d_in[3];
    const float* W2 = (const float*)d_in[4];
    const float* b2 = (const float*)d_in[5];
    const float* Wl = (const float*)d_in[6];
    const float* bl = (const float*)d_in[7];
    float* out = (float*)d_out;

    const int* src = ei;
    const int* dst = ei + N_EDGES;

    float* hws     = (float*)d_ws;                            // N*64
    float* agg     = hws + (size_t)N_NODES * HIDDEN;          // N*64
    int2*  pairs   = (int2*)agg;                              // aliases agg (dead before pull writes agg)
    int*   csr_src = (int*)(agg + (size_t)N_NODES * HIDDEN);  // E
    float* dinv    = (float*)(csr_src + N_EDGES);             // N
    int*   row_ptr = (int*)(dinv + N_NODES);                  // N+4
    int*   buk_cnt = row_ptr + N_NODES + 4;                   // 200
    int*   buk_off = buk_cnt + 200;                           // 200
    int*   bcur    = buk_off + 200;                           // 200

    // --- CSR build (degree counting confined to LDS) ---
    zero_buk_k<<<1, 256, 0, stream>>>(buk_cnt);
    bukhist_k<<<NHB, 256, 0, stream>>>(dst, buk_cnt);
    buk_scan_k<<<1, 256, 0, stream>>>(buk_cnt, buk_off, bcur);
    coarse_k<<<NCB, 256, 0, stream>>>(src, dst, bcur, pairs);
    fine2_k<<<NBUK, 256, 0, stream>>>(pairs, buk_off, csr_src, row_ptr, dinv);

    // --- layer 1 ---
    gemm1_tiled_k<<<GBLK, 256, 0, stream>>>(x, W1, dinv, hws);
    pull_k<<<(N_NODES * 64 + 255) / 256, 256, 0, stream>>>(row_ptr, csr_src, dinv,
                                                           hws, b1, agg);

    // --- layer 2 ---
    gemm2_tiled_k<<<GBLK, 256, 0, stream>>>(agg, W2, dinv, hws);
    pull_k<<<(N_NODES * 64 + 255) / 256, 256, 0, stream>>>(row_ptr, csr_src, dinv,
                                                           hws, b2, agg);

    // --- classifier head ---
    final_k<<<N_NODES / 16, 256, 0, stream>>>(agg, Wl, bl, out);
}

// Round 9
// 352.612 us; speedup vs baseline: 1.1986x; 1.0679x over previous
//
#include <hip/hip_runtime.h>
#include <hip/hip_fp16.h>
#include <math.h>

#define N_NODES 100000
#define N_EDGES 1600000
#define IN_FEAT 128
#define HIDDEN 64
#define N_CLASSES 16

#define TM 64
#define GBLK ((N_NODES + TM - 1) / TM)  // 1563

#define NBUK 196                        // buckets of 512 nodes (dst>>9)
#define CB 4096                         // edges per coarse block
#define NCB ((N_EDGES + CB - 1) / CB)   // 391
#define EPB 1024                        // edges per bukhist block
#define NHB ((N_EDGES + EPB - 1) / EPB) // 1563

// ---------------- bucket histogram (LDS, tiny global flush) ----------------

__global__ void zero_buk_k(int* __restrict__ buk_cnt) {
    if (threadIdx.x < NBUK + 4) buk_cnt[threadIdx.x] = 0;
}

__global__ __launch_bounds__(256) void bukhist_k(const int* __restrict__ dst,
                                                 int* __restrict__ buk_cnt) {
    __shared__ int hist[NBUK + 4];
    int tid = threadIdx.x;
    if (tid < NBUK) hist[tid] = 0;
    __syncthreads();
    int base = blockIdx.x * EPB + tid * 4;
    if (base < N_EDGES) {  // N_EDGES % 4 == 0
        int4 d4 = ((const int4*)dst)[base >> 2];
        atomicAdd(&hist[d4.x >> 9], 1);
        atomicAdd(&hist[d4.y >> 9], 1);
        atomicAdd(&hist[d4.z >> 9], 1);
        atomicAdd(&hist[d4.w >> 9], 1);
    }
    __syncthreads();
    if (tid < NBUK && hist[tid] != 0) atomicAdd(&buk_cnt[tid], hist[tid]);
}

// scan 196 bucket counts -> buk_off (exclusive), init bcur
__global__ __launch_bounds__(256) void buk_scan_k(const int* __restrict__ buk_cnt,
                                                  int* __restrict__ buk_off,
                                                  int* __restrict__ bcur) {
    __shared__ int sm[256];
    int t = threadIdx.x;
    int v = (t < NBUK) ? buk_cnt[t] : 0;
    sm[t] = v;
    __syncthreads();
    for (int s = 1; s < 256; s <<= 1) {
        int add = (t >= s) ? sm[t - s] : 0;
        __syncthreads();
        sm[t] += add;
        __syncthreads();
    }
    if (t < NBUK) {
        int excl = sm[t] - v;
        buk_off[t] = excl;
        bcur[t] = excl;
    }
    if (t == 0) buk_off[NBUK] = N_EDGES;
}

// ---------------- coarse partition: group edges by 512-node bucket ----------------

__global__ __launch_bounds__(256) void coarse_k(const int* __restrict__ src,
                                                const int* __restrict__ dst,
                                                int* __restrict__ bcur,
                                                int2* __restrict__ pairs) {
    __shared__ int hist[NBUK + 4], loff[NBUK + 4], cur[NBUK + 4], gbase[NBUK + 4];
    __shared__ int sc[256];
    __shared__ int2 stage[CB];  // 32 KB
    int tid = threadIdx.x;
    int eb = blockIdx.x * CB;
    int nvalid = N_EDGES - eb;
    if (nvalid > CB) nvalid = CB;

    if (tid < NBUK) hist[tid] = 0;
    __syncthreads();

    int4 s4[4], d4[4];
    #pragma unroll
    for (int q = 0; q < 4; ++q) {
        int e4 = (eb >> 2) + tid + q * 256;
        if (e4 * 4 < N_EDGES) {
            s4[q] = ((const int4*)src)[e4];
            d4[q] = ((const int4*)dst)[e4];
        } else {
            d4[q] = make_int4(-1, -1, -1, -1);
            s4[q] = make_int4(0, 0, 0, 0);
        }
    }
    #pragma unroll
    for (int q = 0; q < 4; ++q) {
        if (d4[q].x >= 0) {
            atomicAdd(&hist[d4[q].x >> 9], 1);
            atomicAdd(&hist[d4[q].y >> 9], 1);
            atomicAdd(&hist[d4[q].z >> 9], 1);
            atomicAdd(&hist[d4[q].w >> 9], 1);
        }
    }
    __syncthreads();

    int v = (tid < NBUK) ? hist[tid] : 0;
    sc[tid] = v;
    __syncthreads();
    for (int s = 1; s < 256; s <<= 1) {
        int add = (tid >= s) ? sc[tid - s] : 0;
        __syncthreads();
        sc[tid] += add;
        __syncthreads();
    }
    if (tid < NBUK) {
        int excl = sc[tid] - v;
        loff[tid] = excl;
        cur[tid] = excl;
        gbase[tid] = atomicAdd(&bcur[tid], v);
    }
    __syncthreads();

    #pragma unroll
    for (int q = 0; q < 4; ++q) {
        if (d4[q].x >= 0) {
            int b, r;
            b = d4[q].x >> 9; r = atomicAdd(&cur[b], 1); stage[r] = make_int2(s4[q].x, d4[q].x);
            b = d4[q].y >> 9; r = atomicAdd(&cur[b], 1); stage[r] = make_int2(s4[q].y, d4[q].y);
            b = d4[q].z >> 9; r = atomicAdd(&cur[b], 1); stage[r] = make_int2(s4[q].z, d4[q].z);
            b = d4[q].w >> 9; r = atomicAdd(&cur[b], 1); stage[r] = make_int2(s4[q].w, d4[q].w);
        }
    }
    __syncthreads();

    for (int i = tid; i < nvalid; i += 256) {
        int2 p = stage[i];
        int b = p.y >> 9;
        pairs[gbase[b] + (i - loff[b])] = p;
    }
}

// ---------------- fine: per-bucket degree count (LDS) + dinv + row_ptr + placement ----------------

__global__ __launch_bounds__(256) void fine2_k(const int2* __restrict__ pairs,
                                               const int* __restrict__ buk_off,
                                               int* __restrict__ csr_src,
                                               int* __restrict__ row_ptr,
                                               float* __restrict__ dinv) {
    __shared__ int cnt[512];
    __shared__ int psc[256];
    __shared__ int cur[512];
    int b = blockIdx.x;
    int node0 = b * 512;
    int nn = N_NODES - node0;
    if (nn > 512) nn = 512;
    int tid = threadIdx.x;

    cnt[tid] = 0; cnt[tid + 256] = 0;
    __syncthreads();

    int e0 = buk_off[b];
    int e1 = buk_off[b + 1];

    for (int e = e0 + tid; e < e1; e += 256)
        atomicAdd(&cnt[pairs[e].y - node0], 1);
    __syncthreads();

    int c0 = cnt[2 * tid], c1 = cnt[2 * tid + 1];
    int p = c0 + c1;
    psc[tid] = p;
    __syncthreads();
    for (int s = 1; s < 256; s <<= 1) {
        int add = (tid >= s) ? psc[tid - s] : 0;
        __syncthreads();
        psc[tid] += add;
        __syncthreads();
    }
    int excl = psc[tid] - p;
    int g0 = e0 + excl;
    int g1 = g0 + c0;
    cur[2 * tid] = g0;
    cur[2 * tid + 1] = g1;
    if (2 * tid < nn) {
        row_ptr[node0 + 2 * tid] = g0;
        dinv[node0 + 2 * tid] = 1.0f / sqrtf((float)(c0 + 1));
    }
    if (2 * tid + 1 < nn) {
        row_ptr[node0 + 2 * tid + 1] = g1;
        dinv[node0 + 2 * tid + 1] = 1.0f / sqrtf((float)(c1 + 1));
    }
    if (b == NBUK - 1 && tid == 0) row_ptr[N_NODES] = N_EDGES;
    __syncthreads();

    for (int e = e0 + tid; e < e1; e += 256) {
        int2 pr = pairs[e];
        int pos = atomicAdd(&cur[pr.y - node0], 1);
        csr_src[pos] = pr.x;
    }
}

// ---------------- register-tiled GEMM 1: hws_h = fp16((x @ W1) * dinv[row]) ----------------

__global__ __launch_bounds__(256) void gemm1_tiled_k(const float* __restrict__ x,
                                                     const float* __restrict__ W,
                                                     const float* __restrict__ dinv,
                                                     __half* __restrict__ hws_h) {
    __shared__ float Ws[64][64];
    __shared__ float xt[64][68];
    int tid = threadIdx.x;
    int row0 = blockIdx.x * TM;
    int rgrp4 = (tid >> 4) * 4;
    int cgrp4 = (tid & 15) * 4;

    float acc[4][4];
    #pragma unroll
    for (int r = 0; r < 4; ++r)
        #pragma unroll
        for (int c = 0; c < 4; ++c) acc[r][c] = 0.0f;

    for (int k0 = 0; k0 < IN_FEAT; k0 += 64) {
        #pragma unroll
        for (int i = 0; i < 4; ++i) {
            int f4 = tid + i * 256;
            int kk = f4 >> 4, c4 = (f4 & 15) * 4;
            *(float4*)&Ws[kk][c4] = *(const float4*)&W[(size_t)(k0 + kk) * HIDDEN + c4];
        }
        #pragma unroll
        for (int i = 0; i < 4; ++i) {
            int f4 = tid + i * 256;
            int rr = f4 >> 4, kq = (f4 & 15) * 4;
            int row = row0 + rr;
            if (row >= N_NODES) row = N_NODES - 1;
            float4 v = *(const float4*)&x[(size_t)row * IN_FEAT + k0 + kq];
            xt[kq + 0][rr] = v.x; xt[kq + 1][rr] = v.y;
            xt[kq + 2][rr] = v.z; xt[kq + 3][rr] = v.w;
        }
        __syncthreads();

        #pragma unroll 16
        for (int kk = 0; kk < 64; ++kk) {
            float4 a = *(const float4*)&xt[kk][rgrp4];
            float4 b = *(const float4*)&Ws[kk][cgrp4];
            acc[0][0] += a.x * b.x; acc[0][1] += a.x * b.y; acc[0][2] += a.x * b.z; acc[0][3] += a.x * b.w;
            acc[1][0] += a.y * b.x; acc[1][1] += a.y * b.y; acc[1][2] += a.y * b.z; acc[1][3] += a.y * b.w;
            acc[2][0] += a.z * b.x; acc[2][1] += a.z * b.y; acc[2][2] += a.z * b.z; acc[2][3] += a.z * b.w;
            acc[3][0] += a.w * b.x; acc[3][1] += a.w * b.y; acc[3][2] += a.w * b.z; acc[3][3] += a.w * b.w;
        }
        __syncthreads();
    }

    #pragma unroll
    for (int r = 0; r < 4; ++r) {
        int row = row0 + rgrp4 + r;
        if (row < N_NODES) {
            float dn = dinv[row];
            __half2* ph = (__half2*)&hws_h[(size_t)row * HIDDEN + cgrp4];
            ph[0] = __floats2half2_rn(acc[r][0] * dn, acc[r][1] * dn);
            ph[1] = __floats2half2_rn(acc[r][2] * dn, acc[r][3] * dn);
        }
    }
}

// ---------------- register-tiled GEMM 2: hws_h = fp16((relu(agg) @ W2) * dinv[row]) ----------------

__global__ __launch_bounds__(256) void gemm2_tiled_k(const float* __restrict__ agg,
                                                     const float* __restrict__ W,
                                                     const float* __restrict__ dinv,
                                                     __half* __restrict__ hws_h) {
    __shared__ float Ws[64][64];
    __shared__ float xt[64][68];
    int tid = threadIdx.x;
    int row0 = blockIdx.x * TM;
    int rgrp4 = (tid >> 4) * 4;
    int cgrp4 = (tid & 15) * 4;

    #pragma unroll
    for (int i = 0; i < 4; ++i) {
        int f4 = tid + i * 256;
        int kk = f4 >> 4, c4 = (f4 & 15) * 4;
        *(float4*)&Ws[kk][c4] = *(const float4*)&W[(size_t)kk * HIDDEN + c4];
    }
    #pragma unroll
    for (int i = 0; i < 4; ++i) {
        int f4 = tid + i * 256;
        int rr = f4 >> 4, kq = (f4 & 15) * 4;
        int row = row0 + rr;
        if (row >= N_NODES) row = N_NODES - 1;
        float4 v = *(const float4*)&agg[(size_t)row * HIDDEN + kq];
        xt[kq + 0][rr] = fmaxf(v.x, 0.f); xt[kq + 1][rr] = fmaxf(v.y, 0.f);
        xt[kq + 2][rr] = fmaxf(v.z, 0.f); xt[kq + 3][rr] = fmaxf(v.w, 0.f);
    }
    __syncthreads();

    float acc[4][4];
    #pragma unroll
    for (int r = 0; r < 4; ++r)
        #pragma unroll
        for (int c = 0; c < 4; ++c) acc[r][c] = 0.0f;

    #pragma unroll 16
    for (int kk = 0; kk < 64; ++kk) {
        float4 a = *(const float4*)&xt[kk][rgrp4];
        float4 b = *(const float4*)&Ws[kk][cgrp4];
        acc[0][0] += a.x * b.x; acc[0][1] += a.x * b.y; acc[0][2] += a.x * b.z; acc[0][3] += a.x * b.w;
        acc[1][0] += a.y * b.x; acc[1][1] += a.y * b.y; acc[1][2] += a.y * b.z; acc[1][3] += a.y * b.w;
        acc[2][0] += a.z * b.x; acc[2][1] += a.z * b.y; acc[2][2] += a.z * b.z; acc[2][3] += a.z * b.w;
        acc[3][0] += a.w * b.x; acc[3][1] += a.w * b.y; acc[3][2] += a.w * b.z; acc[3][3] += a.w * b.w;
    }

    #pragma unroll
    for (int r = 0; r < 4; ++r) {
        int row = row0 + rgrp4 + r;
        if (row < N_NODES) {
            float dn = dinv[row];
            __half2* ph = (__half2*)&hws_h[(size_t)row * HIDDEN + cgrp4];
            ph[0] = __floats2half2_rn(acc[r][0] * dn, acc[r][1] * dn);
            ph[1] = __floats2half2_rn(acc[r][2] * dn, acc[r][3] * dn);
        }
    }
}

// ---------------- CSR pull: agg[d] = b + dinv[d]*(hws[d] + sum_in hws[s]) ----------------
// one wave per node, lane = channel, fp16 rows (128B/gather). Wave-uniform edge
// indices -> scalar loads; guard-free 8/4-wide main loops keep gathers in flight.

__global__ __launch_bounds__(256) void pull_k(const int* __restrict__ row_ptr,
                                              const int* __restrict__ csr_src,
                                              const float* __restrict__ dinv,
                                              const __half* __restrict__ hws_h,
                                              const float* __restrict__ b,
                                              float* __restrict__ agg) {
    int node = (blockIdx.x * 256 + threadIdx.x) >> 6;
    int lane = threadIdx.x & 63;
    if (node >= N_NODES) return;

    int start = row_ptr[node];
    int end   = row_ptr[node + 1];

    float a0 = __half2float(hws_h[(size_t)node * HIDDEN + lane]);  // self-loop term
    float a1 = 0.f, a2 = 0.f, a3 = 0.f, a4 = 0.f, a5 = 0.f, a6 = 0.f, a7 = 0.f;

    int i = start;
    for (; i + 8 <= end; i += 8) {
        int s0 = csr_src[i + 0]; int s1 = csr_src[i + 1];
        int s2 = csr_src[i + 2]; int s3 = csr_src[i + 3];
        int s4 = csr_src[i + 4]; int s5 = csr_src[i + 5];
        int s6 = csr_src[i + 6]; int s7 = csr_src[i + 7];
        a0 += __half2float(hws_h[(size_t)s0 * HIDDEN + lane]);
        a1 += __half2float(hws_h[(size_t)s1 * HIDDEN + lane]);
        a2 += __half2float(hws_h[(size_t)s2 * HIDDEN + lane]);
        a3 += __half2float(hws_h[(size_t)s3 * HIDDEN + lane]);
        a4 += __half2float(hws_h[(size_t)s4 * HIDDEN + lane]);
        a5 += __half2float(hws_h[(size_t)s5 * HIDDEN + lane]);
        a6 += __half2float(hws_h[(size_t)s6 * HIDDEN + lane]);
        a7 += __half2float(hws_h[(size_t)s7 * HIDDEN + lane]);
    }
    for (; i + 4 <= end; i += 4) {
        int s0 = csr_src[i + 0]; int s1 = csr_src[i + 1];
        int s2 = csr_src[i + 2]; int s3 = csr_src[i + 3];
        a0 += __half2float(hws_h[(size_t)s0 * HIDDEN + lane]);
        a1 += __half2float(hws_h[(size_t)s1 * HIDDEN + lane]);
        a2 += __half2float(hws_h[(size_t)s2 * HIDDEN + lane]);
        a3 += __half2float(hws_h[(size_t)s3 * HIDDEN + lane]);
    }
    for (; i < end; ++i) {
        int s = csr_src[i];
        a0 += __half2float(hws_h[(size_t)s * HIDDEN + lane]);
    }

    float sum = ((a0 + a1) + (a2 + a3)) + ((a4 + a5) + (a6 + a7));
    agg[(size_t)node * HIDDEN + lane] = b[lane] + dinv[node] * sum;
}

// ---------------- final: out = relu(agg) @ Wl + bl ----------------

__global__ __launch_bounds__(256) void final_k(const float* __restrict__ agg,
                                               const float* __restrict__ Wl,
                                               const float* __restrict__ bl,
                                               float* __restrict__ out) {
    __shared__ float Ws[HIDDEN * N_CLASSES];
    __shared__ float hs[16][HIDDEN + 1];
    int tid = threadIdx.x;

    if (tid < HIDDEN * N_CLASSES / 4) ((float4*)Ws)[tid] = ((const float4*)Wl)[tid];

    int row0 = blockIdx.x * 16;
    for (int i = tid; i < 16 * HIDDEN; i += 256) {
        int rr = i >> 6;
        int kk = i & 63;
        hs[rr][kk] = fmaxf(agg[(size_t)(row0 + rr) * HIDDEN + kk], 0.0f);
    }
    __syncthreads();

    int col = tid & 15;
    int r = tid >> 4;
    float acc = bl[col];
    #pragma unroll
    for (int k = 0; k < HIDDEN; ++k)
        acc += hs[r][k] * Ws[k * N_CLASSES + col];
    out[(size_t)(row0 + r) * N_CLASSES + col] = acc;
}

// ---------------- launch ----------------

extern "C" void kernel_launch(void* const* d_in, const int* in_sizes, int n_in,
                              void* d_out, int out_size, void* d_ws, size_t ws_size,
                              hipStream_t stream) {
    const float* x  = (const float*)d_in[0];
    const int*   ei = (const int*)d_in[1];
    const float* W1 = (const float*)d_in[2];
    const float* b1 = (const float*)d_in[3];
    const float* W2 = (const float*)d_in[4];
    const float* b2 = (const float*)d_in[5];
    const float* Wl = (const float*)d_in[6];
    const float* bl = (const float*)d_in[7];
    float* out = (float*)d_out;

    const int* src = ei;
    const int* dst = ei + N_EDGES;

    __half* hws_h  = (__half*)d_ws;                              // N*64 halves (12.8 MB)
    float* agg     = (float*)(hws_h + (size_t)N_NODES * HIDDEN); // N*64 floats (25.6 MB)
    int2*  pairs   = (int2*)agg;                                 // aliases agg (dead before pull writes agg)
    int*   csr_src = (int*)(agg + (size_t)N_NODES * HIDDEN);     // E
    float* dinv    = (float*)(csr_src + N_EDGES);                // N
    int*   row_ptr = (int*)(dinv + N_NODES);                     // N+4
    int*   buk_cnt = row_ptr + N_NODES + 4;                      // 200
    int*   buk_off = buk_cnt + 200;                              // 200
    int*   bcur    = buk_off + 200;                              // 200

    // --- CSR build (degree counting confined to LDS) ---
    zero_buk_k<<<1, 256, 0, stream>>>(buk_cnt);
    bukhist_k<<<NHB, 256, 0, stream>>>(dst, buk_cnt);
    buk_scan_k<<<1, 256, 0, stream>>>(buk_cnt, buk_off, bcur);
    coarse_k<<<NCB, 256, 0, stream>>>(src, dst, bcur, pairs);
    fine2_k<<<NBUK, 256, 0, stream>>>(pairs, buk_off, csr_src, row_ptr, dinv);

    // --- layer 1 ---
    gemm1_tiled_k<<<GBLK, 256, 0, stream>>>(x, W1, dinv, hws_h);
    pull_k<<<(N_NODES * 64 + 255) / 256, 256, 0, stream>>>(row_ptr, csr_src, dinv,
                                                           hws_h, b1, agg);

    // --- layer 2 ---
    gemm2_tiled_k<<<GBLK, 256, 0, stream>>>(agg, W2, dinv, hws_h);
    pull_k<<<(N_NODES * 64 + 255) / 256, 256, 0, stream>>>(row_ptr, csr_src, dinv,
                                                           hws_h, b2, agg);

    // --- classifier head ---
    final_k<<<N_NODES / 16, 256, 0, stream>>>(agg, Wl, bl, out);
}